// Round 20
// baseline (507.529 us; speedup 1.0000x reference)
//
#include <hip/hip_runtime.h>
#include <hip/hip_bf16.h>

#define HC   128   // H*C
#define FE   16    // edge feature dim
#define NEG  0.2f
#define SPAD 140   // LDS stride (ushorts) for the per-wave ee tile

using bf16 = __hip_bfloat16;
typedef short s16x8 __attribute__((ext_vector_type(8)));
typedef float f32x4 __attribute__((ext_vector_type(4)));

static __device__ __forceinline__ size_t szt(int a) { return (size_t)a; }
static __device__ __forceinline__ float bl(unsigned u) { return __uint_as_float(u << 16); }
static __device__ __forceinline__ float bh(unsigned u) { return __uint_as_float(u & 0xffff0000u); }
static __device__ __forceinline__ short b16rne(float f) {
    unsigned u = __float_as_uint(f);
    unsigned r = (u + 0x7fffu + ((u >> 16) & 1u)) >> 16;
    return (short)r;
}
static __device__ __forceinline__ unsigned pkbf(float x, float y) {
    return ((unsigned)(unsigned short)b16rne(y) << 16) | (unsigned)(unsigned short)b16rne(x);
}
static __device__ __forceinline__ int xcc_id() {
    int x;
    asm volatile("s_getreg_b32 %0, hwreg(HW_REG_XCC_ID)" : "=s"(x));
    return x & 7;
}

// ---------------- CSR build ----------------
// cnt2[node][8]: one slot per (node, XCD); WORKGROUP-scope (L2-local) atomics.
// k_rank records each edge's (xcd, rank) so k_fill is atomic-free.

__global__ void k_rank(const int* __restrict__ dst, int* __restrict__ cnt2,
                       int* __restrict__ rank, int E) {
    int g = xcc_id();
    int base = (blockIdx.x * 256 + threadIdx.x) * 4;
    if (base >= E) return;
    unsigned gtag = (unsigned)g << 28;
    if (base + 3 < E) {
        int4 d4 = *reinterpret_cast<const int4*>(dst + base);
        int r0 = __hip_atomic_fetch_add(&cnt2[d4.x * 8 + g], 1, __ATOMIC_RELAXED,
                                        __HIP_MEMORY_SCOPE_WORKGROUP);
        int r1 = __hip_atomic_fetch_add(&cnt2[d4.y * 8 + g], 1, __ATOMIC_RELAXED,
                                        __HIP_MEMORY_SCOPE_WORKGROUP);
        int r2 = __hip_atomic_fetch_add(&cnt2[d4.z * 8 + g], 1, __ATOMIC_RELAXED,
                                        __HIP_MEMORY_SCOPE_WORKGROUP);
        int r3 = __hip_atomic_fetch_add(&cnt2[d4.w * 8 + g], 1, __ATOMIC_RELAXED,
                                        __HIP_MEMORY_SCOPE_WORKGROUP);
        *reinterpret_cast<int4*>(rank + base) =
            make_int4(r0 | gtag, r1 | gtag, r2 | gtag, r3 | gtag);
    } else {
        for (int e = base; e < E; ++e) {
            int r = __hip_atomic_fetch_add(&cnt2[dst[e] * 8 + g], 1, __ATOMIC_RELAXED,
                                           __HIP_MEMORY_SCOPE_WORKGROUP);
            rank[e] = r | gtag;
        }
    }
}

__global__ __launch_bounds__(1024) void k_scan1(const int* __restrict__ cnt,
                                                int* __restrict__ excl,
                                                int* __restrict__ bsum, int n) {
    __shared__ int wsum[16];
    int t = threadIdx.x, lane = t & 63, wv = t >> 6;
    int i = blockIdx.x * 4096 + t * 4;
    int4 c = make_int4(0, 0, 0, 0);
    if (i + 3 < n) c = *reinterpret_cast<const int4*>(&cnt[i]);
    else if (i < n) {
        c.x = cnt[i];
        c.y = (i + 1 < n) ? cnt[i + 1] : 0;
        c.z = (i + 2 < n) ? cnt[i + 2] : 0;
    }
    int tot = c.x + c.y + c.z + c.w;
    int s = tot;
    #pragma unroll
    for (int d = 1; d < 64; d <<= 1) { int u = __shfl_up(s, d); if (lane >= d) s += u; }
    if (lane == 63) wsum[wv] = s;
    __syncthreads();
    if (t < 16) {
        int ws = wsum[t];
        #pragma unroll
        for (int d = 1; d < 16; d <<= 1) { int u = __shfl_up(ws, d); if (t >= d) ws += u; }
        wsum[t] = ws;
    }
    __syncthreads();
    int excl_t = (wv ? wsum[wv - 1] : 0) + (s - tot);
    if (i < n) {
        int4 ro;
        ro.x = excl_t;
        ro.y = ro.x + c.x;
        ro.z = ro.y + c.y;
        ro.w = ro.z + c.z;
        if (i + 3 < n) *reinterpret_cast<int4*>(&excl[i]) = ro;
        else {
            excl[i] = ro.x;
            if (i + 1 < n) excl[i + 1] = ro.y;
            if (i + 2 < n) excl[i + 2] = ro.z;
        }
    }
    if (t == 0) bsum[blockIdx.x] = wsum[15];
}

__global__ void k_scan2(int* __restrict__ bsum, int nb) {
    int t = threadIdx.x;   // 64 threads
    int carry = 0;
    for (int base = 0; base < nb; base += 64) {
        int i = base + t;
        int v = (i < nb) ? bsum[i] : 0;
        int s = v;
        #pragma unroll
        for (int d = 1; d < 64; d <<= 1) { int u = __shfl_up(s, d); if (t >= d) s += u; }
        if (i < nb) bsum[i] = carry + s - v;
        carry += __shfl(s, 63);
    }
}

__global__ void k_scan3(const int* __restrict__ bsum, int* __restrict__ off2,
                        int* __restrict__ row_off, int n8, int E) {
    int i = blockIdx.x * 256 + threadIdx.x;
    if (i < n8) {
        int v = off2[i] + bsum[i >> 12];
        off2[i] = v;
        if ((i & 7) == 0) row_off[i >> 3] = v;
    } else if (i == n8) {
        row_off[n8 >> 3] = E;
    }
}

// fill: atomic-free scatter of (src,eid,dst) AND bf16-packed ea row (32B)
__global__ void k_fill(const int* __restrict__ src, const int* __restrict__ dst,
                       const int* __restrict__ rank, const int* __restrict__ off2,
                       const float4* __restrict__ ea_in,
                       int4* __restrict__ pairs4, uint4* __restrict__ eab, int E) {
    int base = (blockIdx.x * 256 + threadIdx.x) * 4;
    if (base >= E) return;
    #pragma unroll
    for (int u = 0; u < 4; ++u) {
        int e = base + u;
        if (e < E) {
            int d = dst[e], k = rank[e];
            int pos = off2[d * 8 + (((unsigned)k) >> 28)] + (k & 0x0FFFFFFF);
            pairs4[pos] = make_int4(src[e], e, d, 0);
            float4 q0 = ea_in[szt(e) * 4 + 0];
            float4 q1 = ea_in[szt(e) * 4 + 1];
            float4 q2 = ea_in[szt(e) * 4 + 2];
            float4 q3 = ea_in[szt(e) * 4 + 3];
            uint4 lo, hi;
            lo.x = pkbf(q0.x, q0.y); lo.y = pkbf(q0.z, q0.w);
            lo.z = pkbf(q1.x, q1.y); lo.w = pkbf(q1.z, q1.w);
            hi.x = pkbf(q2.x, q2.y); hi.y = pkbf(q2.z, q2.w);
            hi.z = pkbf(q3.x, q3.y); hi.w = pkbf(q3.z, q3.w);
            eab[szt(pos) * 2 + 0] = lo;
            eab[szt(pos) * 2 + 1] = hi;
        }
    }
}

// ---------------- weight prep ----------------

__global__ void k_wprep(const float* __restrict__ Wl, const float* __restrict__ Wr,
                        s16x8* __restrict__ Wcf) {
    int idx = blockIdx.x * 256 + threadIdx.x;
    if (idx >= 4096) return;
    int kt = idx >> 10, nt = (idx >> 6) & 15, lane = idx & 63;
    int col = nt * 16 + (lane & 15);
    const float* W = (col < HC) ? Wl : Wr;
    int c = (col < HC) ? col : col - HC;
    s16x8 v;
    #pragma unroll
    for (int j = 0; j < 8; ++j) {
        int k = kt * 32 + (lane >> 4) * 8 + j;
        v[j] = b16rne(W[k * HC + c]);
    }
    Wcf[idx] = v;
}

__global__ void k_wprep2(const float* __restrict__ We, s16x8* __restrict__ Wecf) {
    int idx = blockIdx.x * 256 + threadIdx.x;
    if (idx >= 512) return;
    int lane = idx & 63, g = lane >> 4;
    int ch = (idx >> 6) * 16 + (lane & 15);
    s16x8 v = {0, 0, 0, 0, 0, 0, 0, 0};
    if (g < 2) {
        #pragma unroll
        for (int j = 0; j < 8; ++j)
            v[j] = b16rne(We[(g * 8 + j) * HC + ch]);
    }
    Wecf[idx] = v;
}

// ---------------- projection GEMM via MFMA: [xl|xr] = x @ [Wl|Wr] ----------------

__global__ __launch_bounds__(256) void k_gemm2(const float* __restrict__ x,
                                               const s16x8* __restrict__ Wcf,
                                               bf16* __restrict__ xlb,
                                               bf16* __restrict__ xrb, int n) {
    int t = threadIdx.x, lane = t & 63, w = t >> 6;
    int m0 = blockIdx.x * 16;
    int arow = m0 + (lane & 15);
    if (arow >= n) arow = n - 1;
    const float* xrow = x + szt(arow) * HC + (lane >> 4) * 8;

    f32x4 acc[4];
    #pragma unroll
    for (int nt = 0; nt < 4; ++nt) acc[nt] = (f32x4){0.f, 0.f, 0.f, 0.f};

    #pragma unroll
    for (int kt = 0; kt < 4; ++kt) {
        float4 a0 = *reinterpret_cast<const float4*>(xrow + kt * 32);
        float4 a1 = *reinterpret_cast<const float4*>(xrow + kt * 32 + 4);
        s16x8 af;
        af[0] = b16rne(a0.x); af[1] = b16rne(a0.y);
        af[2] = b16rne(a0.z); af[3] = b16rne(a0.w);
        af[4] = b16rne(a1.x); af[5] = b16rne(a1.y);
        af[6] = b16rne(a1.z); af[7] = b16rne(a1.w);
        #pragma unroll
        for (int nt = 0; nt < 4; ++nt) {
            s16x8 bf = Wcf[(kt * 16 + w * 4 + nt) * 64 + lane];
            acc[nt] = __builtin_amdgcn_mfma_f32_16x16x32_bf16(af, bf, acc[nt], 0, 0, 0);
        }
    }

    bf16* O = (w < 2) ? xlb : xrb;
    int colb = (w & 1) * 64;
    #pragma unroll
    for (int nt = 0; nt < 4; ++nt) {
        int col = colb + nt * 16 + (lane & 15);
        #pragma unroll
        for (int q = 0; q < 4; ++q) {
            int r = m0 + (lane >> 4) * 4 + q;
            if (r < n) O[szt(r) * HC + col] = __float2bfloat16(acc[nt][q]);
        }
    }
}

// ---------------- self-loop: ex_self from mean incoming edge_attr ----------------
// Fully streaming: bf16 ea_csr (eab) read sequentially; no indirection.
// 8 edge slots per wave (j = lane>>3), lane&7 -> one packed feature pair.

__global__ __launch_bounds__(256) void k_self(
    const bf16* __restrict__ xlb, const bf16* __restrict__ xrb,
    const unsigned* __restrict__ eab_u,   // eab as uint stream: 8 uints/edge
    const int* __restrict__ row_off, const float* __restrict__ We,
    const float* __restrict__ att, float* __restrict__ exself, int n)
{
    int lane = threadIdx.x & 63, wv = threadIdx.x >> 6;
    int node = blockIdx.x * 4 + wv;
    if (node >= n) return;
    int beg = row_off[node], end = row_off[node + 1];
    int js = lane >> 3, kp = lane & 7;
    float sx = 0.f, sy = 0.f;
    for (int p = beg + js; p < end; p += 8) {
        unsigned u = eab_u[szt(p) * 8 + kp];
        sx += bl(u); sy += bh(u);
    }
    sx += __shfl_xor(sx, 8);  sy += __shfl_xor(sy, 8);
    sx += __shfl_xor(sx, 16); sy += __shfl_xor(sy, 16);
    sx += __shfl_xor(sx, 32); sy += __shfl_xor(sy, 32);
    int deg = end - beg;
    float invd = (deg > 0) ? 1.f / (float)deg : 0.f;
    float mx = sx * invd, my = sy * invd;   // lane kp holds features (2kp, 2kp+1)

    int c0 = lane * 2, h = lane >> 4;
    float e0 = 0.f, e1 = 0.f;
    #pragma unroll
    for (int q = 0; q < 8; ++q) {
        float ae = __shfl(mx, q);   // feature 2q
        float ao = __shfl(my, q);   // feature 2q+1
        float2 we = *reinterpret_cast<const float2*>(We + (2 * q) * HC + c0);
        float2 wo = *reinterpret_cast<const float2*>(We + (2 * q + 1) * HC + c0);
        e0 += ae * we.x + ao * wo.x;
        e1 += ae * we.y + ao * wo.y;
    }
    unsigned xu = *reinterpret_cast<const unsigned*>(xlb + szt(node) * HC + c0);
    unsigned ru = *reinterpret_cast<const unsigned*>(xrb + szt(node) * HC + c0);
    float2 av = *reinterpret_cast<const float2*>(att + c0);
    float t0 = bl(xu) + bl(ru) + e0; t0 = t0 > 0.f ? t0 : NEG * t0;
    float t1 = bh(xu) + bh(ru) + e1; t1 = t1 > 0.f ? t1 : NEG * t1;
    float part = av.x * t0 + av.y * t1;
    part += __shfl_xor(part, 1);
    part += __shfl_xor(part, 2);
    part += __shfl_xor(part, 4);
    part += __shfl_xor(part, 8);
    float ex = __expf(part);
    if ((lane & 15) == 0) exself[szt(node) * 4 + h] = ex;
}

// ---------------- edge logits (CSR order, MFMA ee + 4-edge-wide epilogue) ----------------
// 16 CSR positions per wave. Phase 1: B-frag = bf16 eab stream (16B/lane,
// coalesced, no conversion) -> 8 MFMAs -> bf16 LDS tile. Phase 2: 4 edges/iter,
// group g -> edge k*4+g, lane -> 8 channels (uint4 loads); xr[dst] rows are
// CSR-sorted (L2-hot).

__global__ __launch_bounds__(256) void k_logit(
    const bf16* __restrict__ xlb, const bf16* __restrict__ xrb,
    const uint4* __restrict__ eab,
    const int4* __restrict__ pairs4,
    const s16x8* __restrict__ Wecf, const float* __restrict__ att,
    float* __restrict__ exe_csr, int E)
{
    __shared__ unsigned short sP[4][16][SPAD];
    int lane = threadIdx.x & 63, wv = threadIdx.x >> 6;
    int p0 = (blockIdx.x * 4 + wv) * 16;
    if (p0 >= E) return;
    unsigned short (*sPw)[SPAD] = sP[wv];

    int ei = lane & 15, g = lane >> 4;
    int p = p0 + ei; if (p >= E) p = E - 1;
    int4 pr = pairs4[p];

    // phase 1: B-frag direct from bf16 stream (K=16 zero-padded to 32)
    s16x8 bfrag = {0, 0, 0, 0, 0, 0, 0, 0};
    if (g < 2)
        bfrag = __builtin_bit_cast(s16x8, eab[szt(p) * 2 + g]);
    #pragma unroll
    for (int mt = 0; mt < 8; ++mt) {
        f32x4 a = __builtin_amdgcn_mfma_f32_16x16x32_bf16(
            Wecf[mt * 64 + lane], bfrag, (f32x4){0.f, 0.f, 0.f, 0.f}, 0, 0, 0);
        // C layout: edge = lane&15, ch = mt*16 + g*4 + q  [on-device verified]
        *reinterpret_cast<uint2*>(&sPw[ei][mt * 16 + g * 4]) =
            make_uint2(pkbf(a[0], a[1]), pkbf(a[2], a[3]));
    }

    // phase 2: 4 edges per iteration (group g -> edge k*4+g; lane l -> 8 ch)
    int l = lane & 15;
    int ch0 = l * 8;
    float4 av0 = *reinterpret_cast<const float4*>(att + ch0);
    float4 av1 = *reinterpret_cast<const float4*>(att + ch0 + 4);
    int m = E - p0; if (m > 16) m = 16;
    #pragma unroll
    for (int k = 0; k < 4; ++k) {
        int j = k * 4 + g;
        int sj = __shfl(pr.x, j);
        int dj = __shfl(pr.z, j);
        uint4 xv = *reinterpret_cast<const uint4*>(xlb + szt(sj) * HC + ch0);
        uint4 rv = *reinterpret_cast<const uint4*>(xrb + szt(dj) * HC + ch0);
        uint4 ev = *reinterpret_cast<const uint4*>(&sPw[j][ch0]);
        float t0 = bl(xv.x) + bl(rv.x) + bl(ev.x); t0 = t0 > 0.f ? t0 : NEG * t0;
        float t1 = bh(xv.x) + bh(rv.x) + bh(ev.x); t1 = t1 > 0.f ? t1 : NEG * t1;
        float t2 = bl(xv.y) + bl(rv.y) + bl(ev.y); t2 = t2 > 0.f ? t2 : NEG * t2;
        float t3 = bh(xv.y) + bh(rv.y) + bh(ev.y); t3 = t3 > 0.f ? t3 : NEG * t3;
        float t4 = bl(xv.z) + bl(rv.z) + bl(ev.z); t4 = t4 > 0.f ? t4 : NEG * t4;
        float t5 = bh(xv.z) + bh(rv.z) + bh(ev.z); t5 = t5 > 0.f ? t5 : NEG * t5;
        float t6 = bl(xv.w) + bl(rv.w) + bl(ev.w); t6 = t6 > 0.f ? t6 : NEG * t6;
        float t7 = bh(xv.w) + bh(rv.w) + bh(ev.w); t7 = t7 > 0.f ? t7 : NEG * t7;
        float part = av0.x * t0 + av0.y * t1 + av0.z * t2 + av0.w * t3
                   + av1.x * t4 + av1.y * t5 + av1.z * t6 + av1.w * t7;
        part += __shfl_xor(part, 1);
        part += __shfl_xor(part, 2);
        if ((lane & 3) == 0 && j < m)
            exe_csr[szt(p0 + j) * 4 + (l >> 2)] = __expf(part);  // logits small: no max-sub
    }
}

// ---------------- aggregation (node-parallel) + alpha write ----------------

__global__ __launch_bounds__(256) void k_aggr(
    const bf16* __restrict__ xlb, const float* __restrict__ exe_csr,
    const float* __restrict__ exself,
    const int4* __restrict__ pairs4, const int* __restrict__ row_off,
    const float* __restrict__ bias, float* __restrict__ out,
    float* __restrict__ alpha, int n, int E)
{
    int lane = threadIdx.x & 63, wv = threadIdx.x >> 6;
    int node = blockIdx.x * 4 + wv;
    if (node >= n) return;
    int j = lane >> 4, cg = lane & 15, cb = cg * 8, h = cg >> 2;
    int beg = row_off[node], end = row_off[node + 1];
    float acc[8];
    #pragma unroll
    for (int i = 0; i < 8; ++i) acc[i] = 0.f;
    float den = 0.f;

    if (beg < end) {
        int last = end - 1;
        int p0 = beg + j; if (p0 > last) p0 = last;
        int4 pr = pairs4[p0];
        float ex = exe_csr[szt(p0) * 4 + h];
        uint4 xv = *reinterpret_cast<const uint4*>(xlb + szt(pr.x) * HC + cb);
        for (int p = beg; p < end; p += 4) {
            int pn = p + 4 + j; if (pn > last) pn = last;
            int4 prN = pairs4[pn];
            float exN = exe_csr[szt(pn) * 4 + h];
            uint4 xvN = *reinterpret_cast<const uint4*>(xlb + szt(prN.x) * HC + cb);
            if (p + j < end) {
                den += ex;
                acc[0] += ex * bl(xv.x); acc[1] += ex * bh(xv.x);
                acc[2] += ex * bl(xv.y); acc[3] += ex * bh(xv.y);
                acc[4] += ex * bl(xv.z); acc[5] += ex * bh(xv.z);
                acc[6] += ex * bl(xv.w); acc[7] += ex * bh(xv.w);
            }
            pr = prN; ex = exN; xv = xvN;
        }
    }
    #pragma unroll
    for (int i = 0; i < 8; ++i) {
        acc[i] += __shfl_xor(acc[i], 16);
        acc[i] += __shfl_xor(acc[i], 32);
    }
    den += __shfl_xor(den, 16);
    den += __shfl_xor(den, 32);

    float exs = exself[szt(node) * 4 + h];
    uint4 xs = *reinterpret_cast<const uint4*>(xlb + szt(node) * HC + cb);
    den += exs;
    acc[0] += exs * bl(xs.x); acc[1] += exs * bh(xs.x);
    acc[2] += exs * bl(xs.y); acc[3] += exs * bh(xs.y);
    acc[4] += exs * bl(xs.z); acc[5] += exs * bh(xs.z);
    acc[6] += exs * bl(xs.w); acc[7] += exs * bh(xs.w);

    float inv = 1.f / den;
    if (j == 0) {
        float4 b0 = *reinterpret_cast<const float4*>(bias + cb);
        float4 b1 = *reinterpret_cast<const float4*>(bias + cb + 4);
        float4 o0, o1;
        o0.x = acc[0] * inv + b0.x; o0.x = o0.x > 0.f ? o0.x : 0.f;
        o0.y = acc[1] * inv + b0.y; o0.y = o0.y > 0.f ? o0.y : 0.f;
        o0.z = acc[2] * inv + b0.z; o0.z = o0.z > 0.f ? o0.z : 0.f;
        o0.w = acc[3] * inv + b0.w; o0.w = o0.w > 0.f ? o0.w : 0.f;
        o1.x = acc[4] * inv + b1.x; o1.x = o1.x > 0.f ? o1.x : 0.f;
        o1.y = acc[5] * inv + b1.y; o1.y = o1.y > 0.f ? o1.y : 0.f;
        o1.z = acc[6] * inv + b1.z; o1.z = o1.z > 0.f ? o1.z : 0.f;
        o1.w = acc[7] * inv + b1.w; o1.w = o1.w > 0.f ? o1.w : 0.f;
        *reinterpret_cast<float4*>(out + szt(node) * HC + cb) = o0;
        *reinterpret_cast<float4*>(out + szt(node) * HC + cb + 4) = o1;
        if ((cg & 3) == 0)
            alpha[szt(E + node) * 4 + h] = exs * inv;
    }
    // normalized alpha for real edges: lane -> (pos lane>>2, head lane&3);
    // head H's inv lives on lanes with cg=4H, j=0 -> lane 4*(lane&3).
    float invh = __shfl(inv, 4 * (lane & 3));
    for (int pp = beg + (lane >> 2); pp < end; pp += 16) {
        int eid = pairs4[pp].y;
        alpha[szt(eid) * 4 + (lane & 3)] = exe_csr[szt(pp) * 4 + (lane & 3)] * invh;
    }
}

// ---------------- launch ----------------

extern "C" void kernel_launch(void* const* d_in, const int* in_sizes, int n_in,
                              void* d_out, int out_size, void* d_ws, size_t ws_size,
                              hipStream_t stream) {
    const float* x    = (const float*)d_in[0];
    const int*   ei   = (const int*)d_in[1];
    const float* ea   = (const float*)d_in[2];
    const float* Wl   = (const float*)d_in[3];
    const float* Wr   = (const float*)d_in[4];
    const float* We   = (const float*)d_in[5];
    const float* att  = (const float*)d_in[6];
    const float* bias = (const float*)d_in[7];

    const int n = in_sizes[0] / HC;   // F_IN == 128
    const int E = in_sizes[1] / 2;
    const int* src = ei;
    const int* dst = ei + E;
    const int n8 = n * 8;

    char* w = (char*)d_ws;
    size_t off = 0;
    auto alloc = [&](size_t bytes) -> char* {
        char* p = w + off;
        off += (bytes + 255) & ~(size_t)255;
        return p;
    };
    bf16*  xlb     = (bf16*) alloc((size_t)n * HC * 2);
    bf16*  xrb     = (bf16*) alloc((size_t)n * HC * 2);
    float* exe_csr = (float*)alloc((size_t)E * 4 * 4);
    float* exself  = (float*)alloc((size_t)n * 4 * 4);
    int*   cnt2    = (int*)  alloc((size_t)n8 * 4);
    int*   off2    = (int*)  alloc((size_t)n8 * 4);
    int*   row_off = (int*)  alloc((size_t)(n + 1) * 4);
    int*   rank    = (int*)  alloc((size_t)E * 4);
    int4*  pairs4  = (int4*) alloc((size_t)E * 16);
    uint4* eab     = (uint4*)alloc((size_t)E * 32);
    s16x8* Wcf     = (s16x8*)alloc((size_t)4096 * 16);
    s16x8* Wecf    = (s16x8*)alloc((size_t)512 * 16);
    int    nb      = (n8 + 4095) / 4096;
    int*   bsum    = (int*)  alloc((size_t)nb * 4);
    (void)ws_size;

    float* out_p   = (float*)d_out;
    float* alpha_p = (float*)d_out + (size_t)n * HC;

    (void)hipMemsetAsync(cnt2, 0, (size_t)n8 * 4, stream);
    k_rank <<<(E / 4 + 255) / 256, 256, 0, stream>>>(dst, cnt2, rank, E);
    k_scan1<<<nb, 1024, 0, stream>>>(cnt2, off2, bsum, n8);
    k_scan2<<<1, 64, 0, stream>>>(bsum, nb);
    k_scan3<<<(n8 + 1 + 255) / 256, 256, 0, stream>>>(bsum, off2, row_off, n8, E);
    k_fill <<<(E / 4 + 255) / 256, 256, 0, stream>>>(src, dst, rank, off2,
                                                     (const float4*)ea, pairs4, eab, E);
    k_wprep<<<16, 256, 0, stream>>>(Wl, Wr, Wcf);
    k_wprep2<<<2, 256, 0, stream>>>(We, Wecf);
    k_gemm2<<<(n + 15) / 16, 256, 0, stream>>>(x, Wcf, xlb, xrb, n);
    k_self <<<(n + 3) / 4, 256, 0, stream>>>(xlb, xrb, (const unsigned*)eab, row_off,
                                             We, att, exself, n);
    k_logit<<<(E + 63) / 64, 256, 0, stream>>>(xlb, xrb, eab, pairs4,
                                               Wecf, att, exe_csr, E);
    k_aggr <<<(n + 3) / 4, 256, 0, stream>>>(xlb, exe_csr, exself, pairs4, row_off,
                                             bias, out_p, alpha_p, n, E);
}

// Round 21
// 468.452 us; speedup vs baseline: 1.0834x; 1.0834x over previous
//
#include <hip/hip_runtime.h>
#include <hip/hip_bf16.h>

#define HC   128   // H*C
#define FE   16    // edge feature dim
#define NEG  0.2f
#define SPAD 140   // LDS stride (ushorts) for the per-wave ee tile

using bf16 = __hip_bfloat16;
using f16  = _Float16;
typedef _Float16 h2 __attribute__((ext_vector_type(2)));
typedef short s16x8 __attribute__((ext_vector_type(8)));
typedef float f32x4 __attribute__((ext_vector_type(4)));

static __device__ __forceinline__ size_t szt(int a) { return (size_t)a; }
static __device__ __forceinline__ short b16rne(float f) {
    unsigned u = __float_as_uint(f);
    unsigned r = (u + 0x7fffu + ((u >> 16) & 1u)) >> 16;
    return (short)r;
}
static __device__ __forceinline__ unsigned pkh(float x, float y) {
    auto h = __builtin_amdgcn_cvt_pkrtz(x, y);   // 2 x f16 packed
    return __builtin_bit_cast(unsigned, h);
}
static __device__ __forceinline__ float hlo(unsigned u) {
    h2 v = __builtin_bit_cast(h2, u); return (float)v.x;
}
static __device__ __forceinline__ float hhi(unsigned u) {
    h2 v = __builtin_bit_cast(h2, u); return (float)v.y;
}
static __device__ __forceinline__ float dot2(h2 a, h2 b, float c) {
#if __has_builtin(__builtin_amdgcn_fdot2)
    return __builtin_amdgcn_fdot2(a, b, c, false);
#else
    return c + (float)a.x * (float)b.x + (float)a.y * (float)b.y;
#endif
}
static __device__ __forceinline__ int xcc_id() {
    int x;
    asm volatile("s_getreg_b32 %0, hwreg(HW_REG_XCC_ID)" : "=s"(x));
    return x & 7;
}

// ---------------- CSR build ----------------
// cnt2[node][8]: one slot per (node, XCD); WORKGROUP-scope (L2-local) atomics.
// k_rank records each edge's (xcd, rank) so k_fill is atomic-free.

__global__ void k_rank(const int* __restrict__ dst, int* __restrict__ cnt2,
                       int* __restrict__ rank, int E) {
    int g = xcc_id();
    int base = (blockIdx.x * 256 + threadIdx.x) * 4;
    if (base >= E) return;
    unsigned gtag = (unsigned)g << 28;
    if (base + 3 < E) {
        int4 d4 = *reinterpret_cast<const int4*>(dst + base);
        int r0 = __hip_atomic_fetch_add(&cnt2[d4.x * 8 + g], 1, __ATOMIC_RELAXED,
                                        __HIP_MEMORY_SCOPE_WORKGROUP);
        int r1 = __hip_atomic_fetch_add(&cnt2[d4.y * 8 + g], 1, __ATOMIC_RELAXED,
                                        __HIP_MEMORY_SCOPE_WORKGROUP);
        int r2 = __hip_atomic_fetch_add(&cnt2[d4.z * 8 + g], 1, __ATOMIC_RELAXED,
                                        __HIP_MEMORY_SCOPE_WORKGROUP);
        int r3 = __hip_atomic_fetch_add(&cnt2[d4.w * 8 + g], 1, __ATOMIC_RELAXED,
                                        __HIP_MEMORY_SCOPE_WORKGROUP);
        *reinterpret_cast<int4*>(rank + base) =
            make_int4(r0 | gtag, r1 | gtag, r2 | gtag, r3 | gtag);
    } else {
        for (int e = base; e < E; ++e) {
            int r = __hip_atomic_fetch_add(&cnt2[dst[e] * 8 + g], 1, __ATOMIC_RELAXED,
                                           __HIP_MEMORY_SCOPE_WORKGROUP);
            rank[e] = r | gtag;
        }
    }
}

__global__ __launch_bounds__(1024) void k_scan1(const int* __restrict__ cnt,
                                                int* __restrict__ excl,
                                                int* __restrict__ bsum, int n) {
    __shared__ int wsum[16];
    int t = threadIdx.x, lane = t & 63, wv = t >> 6;
    int i = blockIdx.x * 4096 + t * 4;
    int4 c = make_int4(0, 0, 0, 0);
    if (i + 3 < n) c = *reinterpret_cast<const int4*>(&cnt[i]);
    else if (i < n) {
        c.x = cnt[i];
        c.y = (i + 1 < n) ? cnt[i + 1] : 0;
        c.z = (i + 2 < n) ? cnt[i + 2] : 0;
    }
    int tot = c.x + c.y + c.z + c.w;
    int s = tot;
    #pragma unroll
    for (int d = 1; d < 64; d <<= 1) { int u = __shfl_up(s, d); if (lane >= d) s += u; }
    if (lane == 63) wsum[wv] = s;
    __syncthreads();
    if (t < 16) {
        int ws = wsum[t];
        #pragma unroll
        for (int d = 1; d < 16; d <<= 1) { int u = __shfl_up(ws, d); if (t >= d) ws += u; }
        wsum[t] = ws;
    }
    __syncthreads();
    int excl_t = (wv ? wsum[wv - 1] : 0) + (s - tot);
    if (i < n) {
        int4 ro;
        ro.x = excl_t;
        ro.y = ro.x + c.x;
        ro.z = ro.y + c.y;
        ro.w = ro.z + c.z;
        if (i + 3 < n) *reinterpret_cast<int4*>(&excl[i]) = ro;
        else {
            excl[i] = ro.x;
            if (i + 1 < n) excl[i + 1] = ro.y;
            if (i + 2 < n) excl[i + 2] = ro.z;
        }
    }
    if (t == 0) bsum[blockIdx.x] = wsum[15];
}

__global__ void k_scan2(int* __restrict__ bsum, int nb) {
    int t = threadIdx.x;   // 64 threads
    int carry = 0;
    for (int base = 0; base < nb; base += 64) {
        int i = base + t;
        int v = (i < nb) ? bsum[i] : 0;
        int s = v;
        #pragma unroll
        for (int d = 1; d < 64; d <<= 1) { int u = __shfl_up(s, d); if (t >= d) s += u; }
        if (i < nb) bsum[i] = carry + s - v;
        carry += __shfl(s, 63);
    }
}

__global__ void k_scan3(const int* __restrict__ bsum, int* __restrict__ off2,
                        int* __restrict__ row_off, int n8, int E) {
    int i = blockIdx.x * 256 + threadIdx.x;
    if (i < n8) {
        int v = off2[i] + bsum[i >> 12];
        off2[i] = v;
        if ((i & 7) == 0) row_off[i >> 3] = v;
    } else if (i == n8) {
        row_off[n8 >> 3] = E;
    }
}

__global__ void k_fill(const int* __restrict__ src, const int* __restrict__ dst,
                       const int* __restrict__ rank, const int* __restrict__ off2,
                       int4* __restrict__ pairs4, int E) {
    int base = (blockIdx.x * 256 + threadIdx.x) * 4;
    if (base >= E) return;
    if (base + 3 < E) {
        int4 d4 = *reinterpret_cast<const int4*>(dst + base);
        int4 s4 = *reinterpret_cast<const int4*>(src + base);
        int4 k4 = *reinterpret_cast<const int4*>(rank + base);
        int p0 = off2[d4.x * 8 + (((unsigned)k4.x) >> 28)] + (k4.x & 0x0FFFFFFF);
        int p1 = off2[d4.y * 8 + (((unsigned)k4.y) >> 28)] + (k4.y & 0x0FFFFFFF);
        int p2 = off2[d4.z * 8 + (((unsigned)k4.z) >> 28)] + (k4.z & 0x0FFFFFFF);
        int p3 = off2[d4.w * 8 + (((unsigned)k4.w) >> 28)] + (k4.w & 0x0FFFFFFF);
        pairs4[p0] = make_int4(s4.x, base + 0, d4.x, 0);
        pairs4[p1] = make_int4(s4.y, base + 1, d4.y, 0);
        pairs4[p2] = make_int4(s4.z, base + 2, d4.z, 0);
        pairs4[p3] = make_int4(s4.w, base + 3, d4.w, 0);
    } else {
        for (int e = base; e < E; ++e) {
            int d = dst[e], k = rank[e];
            int pos = off2[d * 8 + (((unsigned)k) >> 28)] + (k & 0x0FFFFFFF);
            pairs4[pos] = make_int4(src[e], e, d, 0);
        }
    }
}

// ---------------- weight prep ----------------

__global__ void k_wprep(const float* __restrict__ Wl, const float* __restrict__ Wr,
                        s16x8* __restrict__ Wcf) {
    int idx = blockIdx.x * 256 + threadIdx.x;
    if (idx >= 4096) return;
    int kt = idx >> 10, nt = (idx >> 6) & 15, lane = idx & 63;
    int col = nt * 16 + (lane & 15);
    const float* W = (col < HC) ? Wl : Wr;
    int c = (col < HC) ? col : col - HC;
    s16x8 v;
    #pragma unroll
    for (int j = 0; j < 8; ++j) {
        int k = kt * 32 + (lane >> 4) * 8 + j;
        v[j] = b16rne(W[k * HC + c]);
    }
    Wcf[idx] = v;
}

__global__ void k_wprep2(const float* __restrict__ We, s16x8* __restrict__ Wecf) {
    int idx = blockIdx.x * 256 + threadIdx.x;
    if (idx >= 512) return;
    int lane = idx & 63, g = lane >> 4;
    int ch = (idx >> 6) * 16 + (lane & 15);
    s16x8 v = {0, 0, 0, 0, 0, 0, 0, 0};
    if (g < 2) {
        #pragma unroll
        for (int j = 0; j < 8; ++j)
            v[j] = b16rne(We[(g * 8 + j) * HC + ch]);
    }
    Wecf[idx] = v;
}

// ---------------- projection GEMM via MFMA: [xl|xr] = x @ [Wl|Wr] (f16 out) ----------------

__global__ __launch_bounds__(256) void k_gemm2(const float* __restrict__ x,
                                               const s16x8* __restrict__ Wcf,
                                               f16* __restrict__ xlh,
                                               f16* __restrict__ xrh, int n) {
    int t = threadIdx.x, lane = t & 63, w = t >> 6;
    int m0 = blockIdx.x * 16;
    int arow = m0 + (lane & 15);
    if (arow >= n) arow = n - 1;
    const float* xrow = x + szt(arow) * HC + (lane >> 4) * 8;

    f32x4 acc[4];
    #pragma unroll
    for (int nt = 0; nt < 4; ++nt) acc[nt] = (f32x4){0.f, 0.f, 0.f, 0.f};

    #pragma unroll
    for (int kt = 0; kt < 4; ++kt) {
        float4 a0 = *reinterpret_cast<const float4*>(xrow + kt * 32);
        float4 a1 = *reinterpret_cast<const float4*>(xrow + kt * 32 + 4);
        s16x8 af;
        af[0] = b16rne(a0.x); af[1] = b16rne(a0.y);
        af[2] = b16rne(a0.z); af[3] = b16rne(a0.w);
        af[4] = b16rne(a1.x); af[5] = b16rne(a1.y);
        af[6] = b16rne(a1.z); af[7] = b16rne(a1.w);
        #pragma unroll
        for (int nt = 0; nt < 4; ++nt) {
            s16x8 bf = Wcf[(kt * 16 + w * 4 + nt) * 64 + lane];
            acc[nt] = __builtin_amdgcn_mfma_f32_16x16x32_bf16(af, bf, acc[nt], 0, 0, 0);
        }
    }

    f16* O = (w < 2) ? xlh : xrh;
    int colb = (w & 1) * 64;
    #pragma unroll
    for (int nt = 0; nt < 4; ++nt) {
        int col = colb + nt * 16 + (lane & 15);
        #pragma unroll
        for (int q = 0; q < 4; ++q) {
            int r = m0 + (lane >> 4) * 4 + q;
            if (r < n) O[szt(r) * HC + col] = (f16)acc[nt][q];
        }
    }
}

// ---------------- self-loop: ex_self from mean incoming edge_attr ----------------
// 8 edge slots per wave, 1-deep eid prefetch.

__global__ __launch_bounds__(256) void k_self(
    const f16* __restrict__ xlh, const f16* __restrict__ xrh,
    const float* __restrict__ ea, const int4* __restrict__ pairs4,
    const int* __restrict__ row_off, const float* __restrict__ We,
    const float* __restrict__ att, float* __restrict__ exself, int n)
{
    int lane = threadIdx.x & 63, wv = threadIdx.x >> 6;
    int node = blockIdx.x * 4 + wv;
    if (node >= n) return;
    int beg = row_off[node], end = row_off[node + 1];
    int js = lane >> 3, f2 = (lane & 7) * 2;
    float sx = 0.f, sy = 0.f;
    if (beg < end) {
        int last = end - 1;
        int p = beg + js;
        int e_cur = pairs4[(p <= last) ? p : last].y;
        for (; p < end + js; p += 8) {
            int pn = p + 8; if (pn > last) pn = last;
            int e_next = pairs4[pn].y;
            float2 v = *reinterpret_cast<const float2*>(ea + szt(e_cur) * FE + f2);
            if (p < end) { sx += v.x; sy += v.y; }
            e_cur = e_next;
        }
    }
    sx += __shfl_xor(sx, 8);  sy += __shfl_xor(sy, 8);
    sx += __shfl_xor(sx, 16); sy += __shfl_xor(sy, 16);
    sx += __shfl_xor(sx, 32); sy += __shfl_xor(sy, 32);
    int deg = end - beg;
    float invd = (deg > 0) ? 1.f / (float)deg : 0.f;
    float mx = sx * invd, my = sy * invd;   // lane k&7 holds features (2k, 2k+1)

    int c0 = lane * 2, h = lane >> 4;
    float e0 = 0.f, e1 = 0.f;
    #pragma unroll
    for (int kp = 0; kp < 8; ++kp) {
        float ae = __shfl(mx, kp);
        float ao = __shfl(my, kp);
        float2 we = *reinterpret_cast<const float2*>(We + (2 * kp) * HC + c0);
        float2 wo = *reinterpret_cast<const float2*>(We + (2 * kp + 1) * HC + c0);
        e0 += ae * we.x + ao * wo.x;
        e1 += ae * we.y + ao * wo.y;
    }
    unsigned xu = *reinterpret_cast<const unsigned*>(xlh + szt(node) * HC + c0);
    unsigned ru = *reinterpret_cast<const unsigned*>(xrh + szt(node) * HC + c0);
    float2 av = *reinterpret_cast<const float2*>(att + c0);
    float t0 = hlo(xu) + hlo(ru) + e0; t0 = t0 > 0.f ? t0 : NEG * t0;
    float t1 = hhi(xu) + hhi(ru) + e1; t1 = t1 > 0.f ? t1 : NEG * t1;
    float part = av.x * t0 + av.y * t1;
    part += __shfl_xor(part, 1);
    part += __shfl_xor(part, 2);
    part += __shfl_xor(part, 4);
    part += __shfl_xor(part, 8);
    float ex = __expf(part);
    if ((lane & 15) == 0) exself[szt(node) * 4 + h] = ex;
}

// ---------------- edge logits (CSR order, MFMA ee + packed-f16 epilogue) ----------------
// 16 CSR positions per wave. Phase 1: ee = We^T x ea^T via 8 MFMAs -> f16 LDS
// tile. Phase 2: 4 edges/iter, group g -> edge k*4+g, lane -> 8 channels; all
// math packed f16 (pk_add/pk_mul/pk_max + v_dot2_f32_f16): ~20 VALU ops vs 64.

__global__ __launch_bounds__(256) void k_logit(
    const f16* __restrict__ xlh, const f16* __restrict__ xrh,
    const float* __restrict__ ea,
    const int4* __restrict__ pairs4,
    const s16x8* __restrict__ Wecf, const float* __restrict__ att,
    float* __restrict__ exe_csr, int E)
{
    __shared__ unsigned short sP[4][16][SPAD];
    int lane = threadIdx.x & 63, wv = threadIdx.x >> 6;
    int p0 = (blockIdx.x * 4 + wv) * 16;
    if (p0 >= E) return;
    unsigned short (*sPw)[SPAD] = sP[wv];

    int ei = lane & 15, g = lane >> 4;
    int p = p0 + ei; if (p >= E) p = E - 1;
    int4 pr = pairs4[p];

    // phase 1: B-frag = ea row of this lane's edge (K=16 zero-padded to 32)
    s16x8 bfrag = {0, 0, 0, 0, 0, 0, 0, 0};
    if (g < 2) {
        const float* ear = ea + szt(pr.y) * FE + g * 8;
        float4 q0 = *reinterpret_cast<const float4*>(ear);
        float4 q1 = *reinterpret_cast<const float4*>(ear + 4);
        bfrag[0] = b16rne(q0.x); bfrag[1] = b16rne(q0.y);
        bfrag[2] = b16rne(q0.z); bfrag[3] = b16rne(q0.w);
        bfrag[4] = b16rne(q1.x); bfrag[5] = b16rne(q1.y);
        bfrag[6] = b16rne(q1.z); bfrag[7] = b16rne(q1.w);
    }
    #pragma unroll
    for (int mt = 0; mt < 8; ++mt) {
        f32x4 a = __builtin_amdgcn_mfma_f32_16x16x32_bf16(
            Wecf[mt * 64 + lane], bfrag, (f32x4){0.f, 0.f, 0.f, 0.f}, 0, 0, 0);
        // C layout: edge = lane&15, ch = mt*16 + g*4 + q  [on-device verified]
        *reinterpret_cast<uint2*>(&sPw[ei][mt * 16 + g * 4]) =
            make_uint2(pkh(a[0], a[1]), pkh(a[2], a[3]));
    }

    // phase 2: packed-f16; 4 edges/iter (group g -> edge k*4+g; lane l -> 8 ch)
    int l = lane & 15;
    int ch0 = l * 8;
    float4 av0 = *reinterpret_cast<const float4*>(att + ch0);
    float4 av1 = *reinterpret_cast<const float4*>(att + ch0 + 4);
    h2 ah0 = __builtin_bit_cast(h2, pkh(av0.x, av0.y));
    h2 ah1 = __builtin_bit_cast(h2, pkh(av0.z, av0.w));
    h2 ah2 = __builtin_bit_cast(h2, pkh(av1.x, av1.y));
    h2 ah3 = __builtin_bit_cast(h2, pkh(av1.z, av1.w));
    const h2 cneg = {(f16)NEG, (f16)NEG};
    int m = E - p0; if (m > 16) m = 16;
    #pragma unroll
    for (int k = 0; k < 4; ++k) {
        int j = k * 4 + g;
        int sj = __shfl(pr.x, j);
        int dj = __shfl(pr.z, j);
        uint4 xv = *reinterpret_cast<const uint4*>(xlh + szt(sj) * HC + ch0);
        uint4 rv = *reinterpret_cast<const uint4*>(xrh + szt(dj) * HC + ch0);
        uint4 ev = *reinterpret_cast<const uint4*>(&sPw[j][ch0]);
        h2 t0 = __builtin_bit_cast(h2, xv.x) + __builtin_bit_cast(h2, rv.x)
              + __builtin_bit_cast(h2, ev.x);
        h2 t1 = __builtin_bit_cast(h2, xv.y) + __builtin_bit_cast(h2, rv.y)
              + __builtin_bit_cast(h2, ev.y);
        h2 t2 = __builtin_bit_cast(h2, xv.z) + __builtin_bit_cast(h2, rv.z)
              + __builtin_bit_cast(h2, ev.z);
        h2 t3 = __builtin_bit_cast(h2, xv.w) + __builtin_bit_cast(h2, rv.w)
              + __builtin_bit_cast(h2, ev.w);
        t0 = __builtin_elementwise_max(t0, t0 * cneg);
        t1 = __builtin_elementwise_max(t1, t1 * cneg);
        t2 = __builtin_elementwise_max(t2, t2 * cneg);
        t3 = __builtin_elementwise_max(t3, t3 * cneg);
        float part = dot2(t0, ah0, 0.f);
        part = dot2(t1, ah1, part);
        part = dot2(t2, ah2, part);
        part = dot2(t3, ah3, part);
        part += __shfl_xor(part, 1);
        part += __shfl_xor(part, 2);
        if ((lane & 3) == 0 && j < m)
            exe_csr[szt(p0 + j) * 4 + (l >> 2)] = __expf(part);  // logits small: no max-sub
    }
}

// ---------------- aggregation (node-parallel) + alpha write ----------------

__global__ __launch_bounds__(256) void k_aggr(
    const f16* __restrict__ xlh, const float* __restrict__ exe_csr,
    const float* __restrict__ exself,
    const int4* __restrict__ pairs4, const int* __restrict__ row_off,
    const float* __restrict__ bias, float* __restrict__ out,
    float* __restrict__ alpha, int n, int E)
{
    int lane = threadIdx.x & 63, wv = threadIdx.x >> 6;
    int node = blockIdx.x * 4 + wv;
    if (node >= n) return;
    int j = lane >> 4, cg = lane & 15, cb = cg * 8, h = cg >> 2;
    int beg = row_off[node], end = row_off[node + 1];
    float acc[8];
    #pragma unroll
    for (int i = 0; i < 8; ++i) acc[i] = 0.f;
    float den = 0.f;

    if (beg < end) {
        int last = end - 1;
        int p0 = beg + j; if (p0 > last) p0 = last;
        int4 pr = pairs4[p0];
        float ex = exe_csr[szt(p0) * 4 + h];
        uint4 xv = *reinterpret_cast<const uint4*>(xlh + szt(pr.x) * HC + cb);
        for (int p = beg; p < end; p += 4) {
            int pn = p + 4 + j; if (pn > last) pn = last;
            int4 prN = pairs4[pn];
            float exN = exe_csr[szt(pn) * 4 + h];
            uint4 xvN = *reinterpret_cast<const uint4*>(xlh + szt(prN.x) * HC + cb);
            if (p + j < end) {
                den += ex;
                acc[0] += ex * hlo(xv.x); acc[1] += ex * hhi(xv.x);
                acc[2] += ex * hlo(xv.y); acc[3] += ex * hhi(xv.y);
                acc[4] += ex * hlo(xv.z); acc[5] += ex * hhi(xv.z);
                acc[6] += ex * hlo(xv.w); acc[7] += ex * hhi(xv.w);
            }
            pr = prN; ex = exN; xv = xvN;
        }
    }
    #pragma unroll
    for (int i = 0; i < 8; ++i) {
        acc[i] += __shfl_xor(acc[i], 16);
        acc[i] += __shfl_xor(acc[i], 32);
    }
    den += __shfl_xor(den, 16);
    den += __shfl_xor(den, 32);

    float exs = exself[szt(node) * 4 + h];
    uint4 xs = *reinterpret_cast<const uint4*>(xlh + szt(node) * HC + cb);
    den += exs;
    acc[0] += exs * hlo(xs.x); acc[1] += exs * hhi(xs.x);
    acc[2] += exs * hlo(xs.y); acc[3] += exs * hhi(xs.y);
    acc[4] += exs * hlo(xs.z); acc[5] += exs * hhi(xs.z);
    acc[6] += exs * hlo(xs.w); acc[7] += exs * hhi(xs.w);

    float inv = 1.f / den;
    if (j == 0) {
        float4 b0 = *reinterpret_cast<const float4*>(bias + cb);
        float4 b1 = *reinterpret_cast<const float4*>(bias + cb + 4);
        float4 o0, o1;
        o0.x = acc[0] * inv + b0.x; o0.x = o0.x > 0.f ? o0.x : 0.f;
        o0.y = acc[1] * inv + b0.y; o0.y = o0.y > 0.f ? o0.y : 0.f;
        o0.z = acc[2] * inv + b0.z; o0.z = o0.z > 0.f ? o0.z : 0.f;
        o0.w = acc[3] * inv + b0.w; o0.w = o0.w > 0.f ? o0.w : 0.f;
        o1.x = acc[4] * inv + b1.x; o1.x = o1.x > 0.f ? o1.x : 0.f;
        o1.y = acc[5] * inv + b1.y; o1.y = o1.y > 0.f ? o1.y : 0.f;
        o1.z = acc[6] * inv + b1.z; o1.z = o1.z > 0.f ? o1.z : 0.f;
        o1.w = acc[7] * inv + b1.w; o1.w = o1.w > 0.f ? o1.w : 0.f;
        *reinterpret_cast<float4*>(out + szt(node) * HC + cb) = o0;
        *reinterpret_cast<float4*>(out + szt(node) * HC + cb + 4) = o1;
        if ((cg & 3) == 0)
            alpha[szt(E + node) * 4 + h] = exs * inv;
    }
    // normalized alpha for real edges: lane -> (pos lane>>2, head lane&3);
    // head H's inv lives on lanes with cg=4H, j=0 -> lane 4*(lane&3).
    float invh = __shfl(inv, 4 * (lane & 3));
    for (int pp = beg + (lane >> 2); pp < end; pp += 16) {
        int eid = pairs4[pp].y;
        alpha[szt(eid) * 4 + (lane & 3)] = exe_csr[szt(pp) * 4 + (lane & 3)] * invh;
    }
}

// ---------------- launch ----------------

extern "C" void kernel_launch(void* const* d_in, const int* in_sizes, int n_in,
                              void* d_out, int out_size, void* d_ws, size_t ws_size,
                              hipStream_t stream) {
    const float* x    = (const float*)d_in[0];
    const int*   ei   = (const int*)d_in[1];
    const float* ea   = (const float*)d_in[2];
    const float* Wl   = (const float*)d_in[3];
    const float* Wr   = (const float*)d_in[4];
    const float* We   = (const float*)d_in[5];
    const float* att  = (const float*)d_in[6];
    const float* bias = (const float*)d_in[7];

    const int n = in_sizes[0] / HC;   // F_IN == 128
    const int E = in_sizes[1] / 2;
    const int* src = ei;
    const int* dst = ei + E;
    const int n8 = n * 8;

    char* w = (char*)d_ws;
    size_t off = 0;
    auto alloc = [&](size_t bytes) -> char* {
        char* p = w + off;
        off += (bytes + 255) & ~(size_t)255;
        return p;
    };
    f16*   xlh     = (f16*)  alloc((size_t)n * HC * 2);
    f16*   xrh     = (f16*)  alloc((size_t)n * HC * 2);
    float* exe_csr = (float*)alloc((size_t)E * 4 * 4);
    float* exself  = (float*)alloc((size_t)n * 4 * 4);
    int*   cnt2    = (int*)  alloc((size_t)n8 * 4);
    int*   off2    = (int*)  alloc((size_t)n8 * 4);
    int*   row_off = (int*)  alloc((size_t)(n + 1) * 4);
    int*   rank    = (int*)  alloc((size_t)E * 4);
    int4*  pairs4  = (int4*) alloc((size_t)E * 16);
    s16x8* Wcf     = (s16x8*)alloc((size_t)4096 * 16);
    s16x8* Wecf    = (s16x8*)alloc((size_t)512 * 16);
    int    nb      = (n8 + 4095) / 4096;
    int*   bsum    = (int*)  alloc((size_t)nb * 4);
    (void)ws_size;

    float* out_p   = (float*)d_out;
    float* alpha_p = (float*)d_out + (size_t)n * HC;

    (void)hipMemsetAsync(cnt2, 0, (size_t)n8 * 4, stream);
    k_rank <<<(E / 4 + 255) / 256, 256, 0, stream>>>(dst, cnt2, rank, E);
    k_scan1<<<nb, 1024, 0, stream>>>(cnt2, off2, bsum, n8);
    k_scan2<<<1, 64, 0, stream>>>(bsum, nb);
    k_scan3<<<(n8 + 1 + 255) / 256, 256, 0, stream>>>(bsum, off2, row_off, n8, E);
    k_fill <<<(E / 4 + 255) / 256, 256, 0, stream>>>(src, dst, rank, off2, pairs4, E);
    k_wprep<<<16, 256, 0, stream>>>(Wl, Wr, Wcf);
    k_wprep2<<<2, 256, 0, stream>>>(We, Wecf);
    k_gemm2<<<(n + 15) / 16, 256, 0, stream>>>(x, Wcf, xlh, xrh, n);
    k_self <<<(n + 3) / 4, 256, 0, stream>>>(xlh, xrh, ea, pairs4, row_off, We, att,
                                             exself, n);
    k_logit<<<(E + 63) / 64, 256, 0, stream>>>(xlh, xrh, ea, pairs4,
                                               Wecf, att, exe_csr, E);
    k_aggr <<<(n + 3) / 4, 256, 0, stream>>>(xlh, exe_csr, exself, pairs4, row_off,
                                             bias, out_p, alpha_p, n, E);
}

// Round 22
// 462.546 us; speedup vs baseline: 1.0973x; 1.0128x over previous
//
#include <hip/hip_runtime.h>
#include <hip/hip_bf16.h>

#define HC   128   // H*C
#define FE   16    // edge feature dim
#define NEG  0.2f
#define SPAD 140   // LDS stride (ushorts) for the per-wave ee tile

using bf16 = __hip_bfloat16;
using f16  = _Float16;
typedef _Float16 h2 __attribute__((ext_vector_type(2)));
typedef short s16x8 __attribute__((ext_vector_type(8)));
typedef float f32x4 __attribute__((ext_vector_type(4)));

static __device__ __forceinline__ size_t szt(int a) { return (size_t)a; }
static __device__ __forceinline__ short b16rne(float f) {
    unsigned u = __float_as_uint(f);
    unsigned r = (u + 0x7fffu + ((u >> 16) & 1u)) >> 16;
    return (short)r;
}
static __device__ __forceinline__ unsigned pkh(float x, float y) {
    auto h = __builtin_amdgcn_cvt_pkrtz(x, y);   // 2 x f16 packed
    return __builtin_bit_cast(unsigned, h);
}
static __device__ __forceinline__ float hlo(unsigned u) {
    h2 v = __builtin_bit_cast(h2, u); return (float)v.x;
}
static __device__ __forceinline__ float hhi(unsigned u) {
    h2 v = __builtin_bit_cast(h2, u); return (float)v.y;
}
static __device__ __forceinline__ float dot2(h2 a, h2 b, float c) {
#if __has_builtin(__builtin_amdgcn_fdot2)
    return __builtin_amdgcn_fdot2(a, b, c, false);
#else
    return c + (float)a.x * (float)b.x + (float)a.y * (float)b.y;
#endif
}
static __device__ __forceinline__ int xcc_id() {
    int x;
    asm volatile("s_getreg_b32 %0, hwreg(HW_REG_XCC_ID)" : "=s"(x));
    return x & 7;
}

// ---------------- CSR build ----------------
// cnt2[node][8]: one slot per (node, XCD); WORKGROUP-scope (L2-local) atomics.
// k_rank records each edge's (xcd, rank) so k_fill is atomic-free.

__global__ void k_rank(const int* __restrict__ dst, int* __restrict__ cnt2,
                       int* __restrict__ rank, int E) {
    int g = xcc_id();
    int base = (blockIdx.x * 256 + threadIdx.x) * 4;
    if (base >= E) return;
    unsigned gtag = (unsigned)g << 28;
    if (base + 3 < E) {
        int4 d4 = *reinterpret_cast<const int4*>(dst + base);
        int r0 = __hip_atomic_fetch_add(&cnt2[d4.x * 8 + g], 1, __ATOMIC_RELAXED,
                                        __HIP_MEMORY_SCOPE_WORKGROUP);
        int r1 = __hip_atomic_fetch_add(&cnt2[d4.y * 8 + g], 1, __ATOMIC_RELAXED,
                                        __HIP_MEMORY_SCOPE_WORKGROUP);
        int r2 = __hip_atomic_fetch_add(&cnt2[d4.z * 8 + g], 1, __ATOMIC_RELAXED,
                                        __HIP_MEMORY_SCOPE_WORKGROUP);
        int r3 = __hip_atomic_fetch_add(&cnt2[d4.w * 8 + g], 1, __ATOMIC_RELAXED,
                                        __HIP_MEMORY_SCOPE_WORKGROUP);
        *reinterpret_cast<int4*>(rank + base) =
            make_int4(r0 | gtag, r1 | gtag, r2 | gtag, r3 | gtag);
    } else {
        for (int e = base; e < E; ++e) {
            int r = __hip_atomic_fetch_add(&cnt2[dst[e] * 8 + g], 1, __ATOMIC_RELAXED,
                                           __HIP_MEMORY_SCOPE_WORKGROUP);
            rank[e] = r | gtag;
        }
    }
}

__global__ __launch_bounds__(1024) void k_scan1(const int* __restrict__ cnt,
                                                int* __restrict__ excl,
                                                int* __restrict__ bsum, int n) {
    __shared__ int wsum[16];
    int t = threadIdx.x, lane = t & 63, wv = t >> 6;
    int i = blockIdx.x * 4096 + t * 4;
    int4 c = make_int4(0, 0, 0, 0);
    if (i + 3 < n) c = *reinterpret_cast<const int4*>(&cnt[i]);
    else if (i < n) {
        c.x = cnt[i];
        c.y = (i + 1 < n) ? cnt[i + 1] : 0;
        c.z = (i + 2 < n) ? cnt[i + 2] : 0;
    }
    int tot = c.x + c.y + c.z + c.w;
    int s = tot;
    #pragma unroll
    for (int d = 1; d < 64; d <<= 1) { int u = __shfl_up(s, d); if (lane >= d) s += u; }
    if (lane == 63) wsum[wv] = s;
    __syncthreads();
    if (t < 16) {
        int ws = wsum[t];
        #pragma unroll
        for (int d = 1; d < 16; d <<= 1) { int u = __shfl_up(ws, d); if (t >= d) ws += u; }
        wsum[t] = ws;
    }
    __syncthreads();
    int excl_t = (wv ? wsum[wv - 1] : 0) + (s - tot);
    if (i < n) {
        int4 ro;
        ro.x = excl_t;
        ro.y = ro.x + c.x;
        ro.z = ro.y + c.y;
        ro.w = ro.z + c.z;
        if (i + 3 < n) *reinterpret_cast<int4*>(&excl[i]) = ro;
        else {
            excl[i] = ro.x;
            if (i + 1 < n) excl[i + 1] = ro.y;
            if (i + 2 < n) excl[i + 2] = ro.z;
        }
    }
    if (t == 0) bsum[blockIdx.x] = wsum[15];
}

__global__ void k_scan2(int* __restrict__ bsum, int nb) {
    int t = threadIdx.x;   // 64 threads
    int carry = 0;
    for (int base = 0; base < nb; base += 64) {
        int i = base + t;
        int v = (i < nb) ? bsum[i] : 0;
        int s = v;
        #pragma unroll
        for (int d = 1; d < 64; d <<= 1) { int u = __shfl_up(s, d); if (t >= d) s += u; }
        if (i < nb) bsum[i] = carry + s - v;
        carry += __shfl(s, 63);
    }
}

__global__ void k_scan3(const int* __restrict__ bsum, int* __restrict__ off2,
                        int* __restrict__ row_off, int n8, int E) {
    int i = blockIdx.x * 256 + threadIdx.x;
    if (i < n8) {
        int v = off2[i] + bsum[i >> 12];
        off2[i] = v;
        if ((i & 7) == 0) row_off[i >> 3] = v;
    } else if (i == n8) {
        row_off[n8 >> 3] = E;
    }
}

__global__ void k_fill(const int* __restrict__ src, const int* __restrict__ dst,
                       const int* __restrict__ rank, const int* __restrict__ off2,
                       int4* __restrict__ pairs4, int E) {
    int base = (blockIdx.x * 256 + threadIdx.x) * 4;
    if (base >= E) return;
    if (base + 3 < E) {
        int4 d4 = *reinterpret_cast<const int4*>(dst + base);
        int4 s4 = *reinterpret_cast<const int4*>(src + base);
        int4 k4 = *reinterpret_cast<const int4*>(rank + base);
        int p0 = off2[d4.x * 8 + (((unsigned)k4.x) >> 28)] + (k4.x & 0x0FFFFFFF);
        int p1 = off2[d4.y * 8 + (((unsigned)k4.y) >> 28)] + (k4.y & 0x0FFFFFFF);
        int p2 = off2[d4.z * 8 + (((unsigned)k4.z) >> 28)] + (k4.z & 0x0FFFFFFF);
        int p3 = off2[d4.w * 8 + (((unsigned)k4.w) >> 28)] + (k4.w & 0x0FFFFFFF);
        pairs4[p0] = make_int4(s4.x, base + 0, d4.x, 0);
        pairs4[p1] = make_int4(s4.y, base + 1, d4.y, 0);
        pairs4[p2] = make_int4(s4.z, base + 2, d4.z, 0);
        pairs4[p3] = make_int4(s4.w, base + 3, d4.w, 0);
    } else {
        for (int e = base; e < E; ++e) {
            int d = dst[e], k = rank[e];
            int pos = off2[d * 8 + (((unsigned)k) >> 28)] + (k & 0x0FFFFFFF);
            pairs4[pos] = make_int4(src[e], e, d, 0);
        }
    }
}

// ---------------- weight prep ----------------

__global__ void k_wprep(const float* __restrict__ Wl, const float* __restrict__ Wr,
                        s16x8* __restrict__ Wcf) {
    int idx = blockIdx.x * 256 + threadIdx.x;
    if (idx >= 4096) return;
    int kt = idx >> 10, nt = (idx >> 6) & 15, lane = idx & 63;
    int col = nt * 16 + (lane & 15);
    const float* W = (col < HC) ? Wl : Wr;
    int c = (col < HC) ? col : col - HC;
    s16x8 v;
    #pragma unroll
    for (int j = 0; j < 8; ++j) {
        int k = kt * 32 + (lane >> 4) * 8 + j;
        v[j] = b16rne(W[k * HC + c]);
    }
    Wcf[idx] = v;
}

__global__ void k_wprep2(const float* __restrict__ We, s16x8* __restrict__ Wecf) {
    int idx = blockIdx.x * 256 + threadIdx.x;
    if (idx >= 512) return;
    int lane = idx & 63, g = lane >> 4;
    int ch = (idx >> 6) * 16 + (lane & 15);
    s16x8 v = {0, 0, 0, 0, 0, 0, 0, 0};
    if (g < 2) {
        #pragma unroll
        for (int j = 0; j < 8; ++j)
            v[j] = b16rne(We[(g * 8 + j) * HC + ch]);
    }
    Wecf[idx] = v;
}

// ---------------- projection GEMM via MFMA: [xl|xr] = x @ [Wl|Wr] (f16 out) ----------------

__global__ __launch_bounds__(256) void k_gemm2(const float* __restrict__ x,
                                               const s16x8* __restrict__ Wcf,
                                               f16* __restrict__ xlh,
                                               f16* __restrict__ xrh, int n) {
    int t = threadIdx.x, lane = t & 63, w = t >> 6;
    int m0 = blockIdx.x * 16;
    int arow = m0 + (lane & 15);
    if (arow >= n) arow = n - 1;
    const float* xrow = x + szt(arow) * HC + (lane >> 4) * 8;

    f32x4 acc[4];
    #pragma unroll
    for (int nt = 0; nt < 4; ++nt) acc[nt] = (f32x4){0.f, 0.f, 0.f, 0.f};

    #pragma unroll
    for (int kt = 0; kt < 4; ++kt) {
        float4 a0 = *reinterpret_cast<const float4*>(xrow + kt * 32);
        float4 a1 = *reinterpret_cast<const float4*>(xrow + kt * 32 + 4);
        s16x8 af;
        af[0] = b16rne(a0.x); af[1] = b16rne(a0.y);
        af[2] = b16rne(a0.z); af[3] = b16rne(a0.w);
        af[4] = b16rne(a1.x); af[5] = b16rne(a1.y);
        af[6] = b16rne(a1.z); af[7] = b16rne(a1.w);
        #pragma unroll
        for (int nt = 0; nt < 4; ++nt) {
            s16x8 bf = Wcf[(kt * 16 + w * 4 + nt) * 64 + lane];
            acc[nt] = __builtin_amdgcn_mfma_f32_16x16x32_bf16(af, bf, acc[nt], 0, 0, 0);
        }
    }

    f16* O = (w < 2) ? xlh : xrh;
    int colb = (w & 1) * 64;
    #pragma unroll
    for (int nt = 0; nt < 4; ++nt) {
        int col = colb + nt * 16 + (lane & 15);
        #pragma unroll
        for (int q = 0; q < 4; ++q) {
            int r = m0 + (lane >> 4) * 4 + q;
            if (r < n) O[szt(r) * HC + col] = (f16)acc[nt][q];
        }
    }
}

// ---------------- self-loop: ex_self from mean incoming edge_attr ----------------
// 16 edge slots per wave: lane = (slot lane>>2, feature-quad lane&3), float4
// loads -> 16 independent rows in flight. 1-deep eid prefetch.  [R21: 8 slots
// at 109us, latency-bound]

__global__ __launch_bounds__(256) void k_self(
    const f16* __restrict__ xlh, const f16* __restrict__ xrh,
    const float* __restrict__ ea, const int4* __restrict__ pairs4,
    const int* __restrict__ row_off, const float* __restrict__ We,
    const float* __restrict__ att, float* __restrict__ exself, int n)
{
    int lane = threadIdx.x & 63, wv = threadIdx.x >> 6;
    int node = blockIdx.x * 4 + wv;
    if (node >= n) return;
    int beg = row_off[node], end = row_off[node + 1];
    int js = lane >> 2, fq = (lane & 3) * 4;
    float4 s4 = make_float4(0.f, 0.f, 0.f, 0.f);
    if (beg < end) {
        int last = end - 1;
        int p = beg + js;
        int e_cur = pairs4[(p <= last) ? p : last].y;
        for (; p < end + js; p += 16) {
            int pn = p + 16; if (pn > last) pn = last;
            int e_next = pairs4[pn].y;
            float4 v = *reinterpret_cast<const float4*>(ea + szt(e_cur) * FE + fq);
            if (p < end) { s4.x += v.x; s4.y += v.y; s4.z += v.z; s4.w += v.w; }
            e_cur = e_next;
        }
    }
    // reduce over slot bits (lane bits 2..5): lane l ends with quad (l&3) sum
    #pragma unroll
    for (int d = 4; d < 64; d <<= 1) {
        s4.x += __shfl_xor(s4.x, d);
        s4.y += __shfl_xor(s4.y, d);
        s4.z += __shfl_xor(s4.z, d);
        s4.w += __shfl_xor(s4.w, d);
    }
    int deg = end - beg;
    float invd = (deg > 0) ? 1.f / (float)deg : 0.f;
    float4 m4 = make_float4(s4.x * invd, s4.y * invd, s4.z * invd, s4.w * invd);

    int c0 = lane * 2, h = lane >> 4;
    float e0 = 0.f, e1 = 0.f;
    // feature kp = element kp&3 of the quad held by lane kp>>2
    #pragma unroll
    for (int kp = 0; kp < FE; ++kp) {
        float a;
        switch (kp & 3) {
            case 0: a = __shfl(m4.x, kp >> 2); break;
            case 1: a = __shfl(m4.y, kp >> 2); break;
            case 2: a = __shfl(m4.z, kp >> 2); break;
            default: a = __shfl(m4.w, kp >> 2); break;
        }
        float2 w = *reinterpret_cast<const float2*>(We + kp * HC + c0);
        e0 += a * w.x;
        e1 += a * w.y;
    }
    unsigned xu = *reinterpret_cast<const unsigned*>(xlh + szt(node) * HC + c0);
    unsigned ru = *reinterpret_cast<const unsigned*>(xrh + szt(node) * HC + c0);
    float2 av = *reinterpret_cast<const float2*>(att + c0);
    float t0 = hlo(xu) + hlo(ru) + e0; t0 = t0 > 0.f ? t0 : NEG * t0;
    float t1 = hhi(xu) + hhi(ru) + e1; t1 = t1 > 0.f ? t1 : NEG * t1;
    float part = av.x * t0 + av.y * t1;
    part += __shfl_xor(part, 1);
    part += __shfl_xor(part, 2);
    part += __shfl_xor(part, 4);
    part += __shfl_xor(part, 8);
    float ex = __expf(part);
    if ((lane & 15) == 0) exself[szt(node) * 4 + h] = ex;
}

// ---------------- edge logits (CSR order, MFMA ee + packed-f16 epilogue) ----------------

__global__ __launch_bounds__(256) void k_logit(
    const f16* __restrict__ xlh, const f16* __restrict__ xrh,
    const float* __restrict__ ea,
    const int4* __restrict__ pairs4,
    const s16x8* __restrict__ Wecf, const float* __restrict__ att,
    float* __restrict__ exe_csr, int E)
{
    __shared__ unsigned short sP[4][16][SPAD];
    int lane = threadIdx.x & 63, wv = threadIdx.x >> 6;
    int p0 = (blockIdx.x * 4 + wv) * 16;
    if (p0 >= E) return;
    unsigned short (*sPw)[SPAD] = sP[wv];

    int ei = lane & 15, g = lane >> 4;
    int p = p0 + ei; if (p >= E) p = E - 1;
    int4 pr = pairs4[p];

    // phase 1: B-frag = ea row of this lane's edge (K=16 zero-padded to 32)
    s16x8 bfrag = {0, 0, 0, 0, 0, 0, 0, 0};
    if (g < 2) {
        const float* ear = ea + szt(pr.y) * FE + g * 8;
        float4 q0 = *reinterpret_cast<const float4*>(ear);
        float4 q1 = *reinterpret_cast<const float4*>(ear + 4);
        bfrag[0] = b16rne(q0.x); bfrag[1] = b16rne(q0.y);
        bfrag[2] = b16rne(q0.z); bfrag[3] = b16rne(q0.w);
        bfrag[4] = b16rne(q1.x); bfrag[5] = b16rne(q1.y);
        bfrag[6] = b16rne(q1.z); bfrag[7] = b16rne(q1.w);
    }
    #pragma unroll
    for (int mt = 0; mt < 8; ++mt) {
        f32x4 a = __builtin_amdgcn_mfma_f32_16x16x32_bf16(
            Wecf[mt * 64 + lane], bfrag, (f32x4){0.f, 0.f, 0.f, 0.f}, 0, 0, 0);
        // C layout: edge = lane&15, ch = mt*16 + g*4 + q  [on-device verified]
        *reinterpret_cast<uint2*>(&sPw[ei][mt * 16 + g * 4]) =
            make_uint2(pkh(a[0], a[1]), pkh(a[2], a[3]));
    }

    // phase 2: packed-f16; 4 edges/iter (group g -> edge k*4+g; lane l -> 8 ch)
    int l = lane & 15;
    int ch0 = l * 8;
    float4 av0 = *reinterpret_cast<const float4*>(att + ch0);
    float4 av1 = *reinterpret_cast<const float4*>(att + ch0 + 4);
    h2 ah0 = __builtin_bit_cast(h2, pkh(av0.x, av0.y));
    h2 ah1 = __builtin_bit_cast(h2, pkh(av0.z, av0.w));
    h2 ah2 = __builtin_bit_cast(h2, pkh(av1.x, av1.y));
    h2 ah3 = __builtin_bit_cast(h2, pkh(av1.z, av1.w));
    const h2 cneg = {(f16)NEG, (f16)NEG};
    int m = E - p0; if (m > 16) m = 16;
    #pragma unroll
    for (int k = 0; k < 4; ++k) {
        int j = k * 4 + g;
        int sj = __shfl(pr.x, j);
        int dj = __shfl(pr.z, j);
        uint4 xv = *reinterpret_cast<const uint4*>(xlh + szt(sj) * HC + ch0);
        uint4 rv = *reinterpret_cast<const uint4*>(xrh + szt(dj) * HC + ch0);
        uint4 ev = *reinterpret_cast<const uint4*>(&sPw[j][ch0]);
        h2 t0 = __builtin_bit_cast(h2, xv.x) + __builtin_bit_cast(h2, rv.x)
              + __builtin_bit_cast(h2, ev.x);
        h2 t1 = __builtin_bit_cast(h2, xv.y) + __builtin_bit_cast(h2, rv.y)
              + __builtin_bit_cast(h2, ev.y);
        h2 t2 = __builtin_bit_cast(h2, xv.z) + __builtin_bit_cast(h2, rv.z)
              + __builtin_bit_cast(h2, ev.z);
        h2 t3 = __builtin_bit_cast(h2, xv.w) + __builtin_bit_cast(h2, rv.w)
              + __builtin_bit_cast(h2, ev.w);
        t0 = __builtin_elementwise_max(t0, t0 * cneg);
        t1 = __builtin_elementwise_max(t1, t1 * cneg);
        t2 = __builtin_elementwise_max(t2, t2 * cneg);
        t3 = __builtin_elementwise_max(t3, t3 * cneg);
        float part = dot2(t0, ah0, 0.f);
        part = dot2(t1, ah1, part);
        part = dot2(t2, ah2, part);
        part = dot2(t3, ah3, part);
        part += __shfl_xor(part, 1);
        part += __shfl_xor(part, 2);
        if ((lane & 3) == 0 && j < m)
            exe_csr[szt(p0 + j) * 4 + (l >> 2)] = __expf(part);  // logits small: no max-sub
    }
}

// ---------------- aggregation (node-parallel) + alpha write ----------------

__global__ __launch_bounds__(256) void k_aggr(
    const f16* __restrict__ xlh, const float* __restrict__ exe_csr,
    const float* __restrict__ exself,
    const int4* __restrict__ pairs4, const int* __restrict__ row_off,
    const float* __restrict__ bias, float* __restrict__ out,
    float* __restrict__ alpha, int n, int E)
{
    int lane = threadIdx.x & 63, wv = threadIdx.x >> 6;
    int node = blockIdx.x * 4 + wv;
    if (node >= n) return;
    int j = lane >> 4, cg = lane & 15, cb = cg * 8, h = cg >> 2;
    int beg = row_off[node], end = row_off[node + 1];
    float acc[8];
    #pragma unroll
    for (int i = 0; i < 8; ++i) acc[i] = 0.f;
    float den = 0.f;

    if (beg < end) {
        int last = end - 1;
        int p0 = beg + j; if (p0 > last) p0 = last;
        int4 pr = pairs4[p0];
        float ex = exe_csr[szt(p0) * 4 + h];
        uint4 xv = *reinterpret_cast<const uint4*>(xlh + szt(pr.x) * HC + cb);
        for (int p = beg; p < end; p += 4) {
            int pn = p + 4 + j; if (pn > last) pn = last;
            int4 prN = pairs4[pn];
            float exN = exe_csr[szt(pn) * 4 + h];
            uint4 xvN = *reinterpret_cast<const uint4*>(xlh + szt(prN.x) * HC + cb);
            if (p + j < end) {
                den += ex;
                acc[0] += ex * hlo(xv.x); acc[1] += ex * hhi(xv.x);
                acc[2] += ex * hlo(xv.y); acc[3] += ex * hhi(xv.y);
                acc[4] += ex * hlo(xv.z); acc[5] += ex * hhi(xv.z);
                acc[6] += ex * hlo(xv.w); acc[7] += ex * hhi(xv.w);
            }
            pr = prN; ex = exN; xv = xvN;
        }
    }
    #pragma unroll
    for (int i = 0; i < 8; ++i) {
        acc[i] += __shfl_xor(acc[i], 16);
        acc[i] += __shfl_xor(acc[i], 32);
    }
    den += __shfl_xor(den, 16);
    den += __shfl_xor(den, 32);

    float exs = exself[szt(node) * 4 + h];
    uint4 xs = *reinterpret_cast<const uint4*>(xlh + szt(node) * HC + cb);
    den += exs;
    acc[0] += exs * hlo(xs.x); acc[1] += exs * hhi(xs.x);
    acc[2] += exs * hlo(xs.y); acc[3] += exs * hhi(xs.y);
    acc[4] += exs * hlo(xs.z); acc[5] += exs * hhi(xs.z);
    acc[6] += exs * hlo(xs.w); acc[7] += exs * hhi(xs.w);

    float inv = 1.f / den;
    if (j == 0) {
        float4 b0 = *reinterpret_cast<const float4*>(bias + cb);
        float4 b1 = *reinterpret_cast<const float4*>(bias + cb + 4);
        float4 o0, o1;
        o0.x = acc[0] * inv + b0.x; o0.x = o0.x > 0.f ? o0.x : 0.f;
        o0.y = acc[1] * inv + b0.y; o0.y = o0.y > 0.f ? o0.y : 0.f;
        o0.z = acc[2] * inv + b0.z; o0.z = o0.z > 0.f ? o0.z : 0.f;
        o0.w = acc[3] * inv + b0.w; o0.w = o0.w > 0.f ? o0.w : 0.f;
        o1.x = acc[4] * inv + b1.x; o1.x = o1.x > 0.f ? o1.x : 0.f;
        o1.y = acc[5] * inv + b1.y; o1.y = o1.y > 0.f ? o1.y : 0.f;
        o1.z = acc[6] * inv + b1.z; o1.z = o1.z > 0.f ? o1.z : 0.f;
        o1.w = acc[7] * inv + b1.w; o1.w = o1.w > 0.f ? o1.w : 0.f;
        *reinterpret_cast<float4*>(out + szt(node) * HC + cb) = o0;
        *reinterpret_cast<float4*>(out + szt(node) * HC + cb + 4) = o1;
        if ((cg & 3) == 0)
            alpha[szt(E + node) * 4 + h] = exs * inv;
    }
    // normalized alpha for real edges: lane -> (pos lane>>2, head lane&3);
    // head H's inv lives on lanes with cg=4H, j=0 -> lane 4*(lane&3).
    float invh = __shfl(inv, 4 * (lane & 3));
    for (int pp = beg + (lane >> 2); pp < end; pp += 16) {
        int eid = pairs4[pp].y;
        alpha[szt(eid) * 4 + (lane & 3)] = exe_csr[szt(pp) * 4 + (lane & 3)] * invh;
    }
}

// ---------------- launch ----------------

extern "C" void kernel_launch(void* const* d_in, const int* in_sizes, int n_in,
                              void* d_out, int out_size, void* d_ws, size_t ws_size,
                              hipStream_t stream) {
    const float* x    = (const float*)d_in[0];
    const int*   ei   = (const int*)d_in[1];
    const float* ea   = (const float*)d_in[2];
    const float* Wl   = (const float*)d_in[3];
    const float* Wr   = (const float*)d_in[4];
    const float* We   = (const float*)d_in[5];
    const float* att  = (const float*)d_in[6];
    const float* bias = (const float*)d_in[7];

    const int n = in_sizes[0] / HC;   // F_IN == 128
    const int E = in_sizes[1] / 2;
    const int* src = ei;
    const int* dst = ei + E;
    const int n8 = n * 8;

    char* w = (char*)d_ws;
    size_t off = 0;
    auto alloc = [&](size_t bytes) -> char* {
        char* p = w + off;
        off += (bytes + 255) & ~(size_t)255;
        return p;
    };
    f16*   xlh     = (f16*)  alloc((size_t)n * HC * 2);
    f16*   xrh     = (f16*)  alloc((size_t)n * HC * 2);
    float* exe_csr = (float*)alloc((size_t)E * 4 * 4);
    float* exself  = (float*)alloc((size_t)n * 4 * 4);
    int*   cnt2    = (int*)  alloc((size_t)n8 * 4);
    int*   off2    = (int*)  alloc((size_t)n8 * 4);
    int*   row_off = (int*)  alloc((size_t)(n + 1) * 4);
    int*   rank    = (int*)  alloc((size_t)E * 4);
    int4*  pairs4  = (int4*) alloc((size_t)E * 16);
    s16x8* Wcf     = (s16x8*)alloc((size_t)4096 * 16);
    s16x8* Wecf    = (s16x8*)alloc((size_t)512 * 16);
    int    nb      = (n8 + 4095) / 4096;
    int*   bsum    = (int*)  alloc((size_t)nb * 4);
    (void)ws_size;

    float* out_p   = (float*)d_out;
    float* alpha_p = (float*)d_out + (size_t)n * HC;

    (void)hipMemsetAsync(cnt2, 0, (size_t)n8 * 4, stream);
    k_rank <<<(E / 4 + 255) / 256, 256, 0, stream>>>(dst, cnt2, rank, E);
    k_scan1<<<nb, 1024, 0, stream>>>(cnt2, off2, bsum, n8);
    k_scan2<<<1, 64, 0, stream>>>(bsum, nb);
    k_scan3<<<(n8 + 1 + 255) / 256, 256, 0, stream>>>(bsum, off2, row_off, n8, E);
    k_fill <<<(E / 4 + 255) / 256, 256, 0, stream>>>(src, dst, rank, off2, pairs4, E);
    k_wprep<<<16, 256, 0, stream>>>(Wl, Wr, Wcf);
    k_wprep2<<<2, 256, 0, stream>>>(We, Wecf);
    k_gemm2<<<(n + 15) / 16, 256, 0, stream>>>(x, Wcf, xlh, xrh, n);
    k_self <<<(n + 3) / 4, 256, 0, stream>>>(xlh, xrh, ea, pairs4, row_off, We, att,
                                             exself, n);
    k_logit<<<(E + 63) / 64, 256, 0, stream>>>(xlh, xrh, ea, pairs4,
                                               Wecf, att, exe_csr, E);
    k_aggr <<<(n + 3) / 4, 256, 0, stream>>>(xlh, exe_csr, exself, pairs4, row_off,
                                             bias, out_p, alpha_p, n, E);
}